// Round 2
// baseline (52960.291 us; speedup 1.0000x reference)
//
#include <hip/hip_runtime.h>

// LSTM: V=32000, E=512, H=512, OUT=2, L=2, S=512, B=64
// Persistent cooperative kernel. 256 blocks x 512 threads.
// Block owns 2 h-rows (8 gate-rows: gates ordered f,i,c,o; gr = g*2+rr).
// Layer-1 weights folded: for l>=1, x==h so W@[h;x] = (W[:,:H]+W[:,H:])@h.
// c stays in LDS (block-exclusive rows).
// h PING-PONGS between two global buffers: phase 0 reads h[0] writes h[1];
// phase 1 reads h[1] writes h[0]. Removes the write-while-others-read race.

constexpr int Hn = 512, En = 512, Bn = 64, Sn = 512, OUTn = 2;
constexpr int NBLOCKS = 256;
constexpr int NTHREADS = 512;

__device__ __forceinline__ void grid_sync(unsigned* cnt, unsigned* gen) {
  __syncthreads();
  if (threadIdx.x == 0) {
    __threadfence();  // release: flush this block's h stores (post-syncthreads, cumulative)
    unsigned g = __hip_atomic_load(gen, __ATOMIC_RELAXED, __HIP_MEMORY_SCOPE_AGENT);
    unsigned a = __hip_atomic_fetch_add(cnt, 1u, __ATOMIC_ACQ_REL, __HIP_MEMORY_SCOPE_AGENT);
    if (a == NBLOCKS - 1) {
      __hip_atomic_store(cnt, 0u, __ATOMIC_RELAXED, __HIP_MEMORY_SCOPE_AGENT);
      __hip_atomic_store(gen, g + 1u, __ATOMIC_RELEASE, __HIP_MEMORY_SCOPE_AGENT);
    } else {
      while (__hip_atomic_load(gen, __ATOMIC_RELAXED, __HIP_MEMORY_SCOPE_AGENT) == g) {
        __builtin_amdgcn_s_sleep(2);
      }
    }
    __threadfence();  // acquire: invalidate L1/L2 so h reads are fresh
  }
  __syncthreads();
}

__device__ __forceinline__ float sigmoidf_(float x) { return 1.f / (1.f + expf(-x)); }

__global__ void __launch_bounds__(NTHREADS, 2) lstm_persistent(
    const int* __restrict__ texts, const float* __restrict__ emb,
    const float* __restrict__ Wf, const float* __restrict__ bf,
    const float* __restrict__ Wi, const float* __restrict__ bi,
    const float* __restrict__ Wo, const float* __restrict__ bo,
    const float* __restrict__ Wc, const float* __restrict__ bc,
    const float* __restrict__ Wy, const float* __restrict__ by,
    float* __restrict__ out, float* __restrict__ h0buf, float* __restrict__ h1buf,
    unsigned* cnt, unsigned* gen)
{
  __shared__ float sW0[8][En + Hn];   // 32 KB: layer-0 weights for 8 gate-rows
  __shared__ float sW1[8][Hn];        // 16 KB: folded layer-1 weights
  __shared__ float sA[8][Bn];         // gate pre-activations
  __shared__ float sC[2][Bn];         // cell state for this block's 2 rows
  __shared__ float sBias[2][8];

  const int tid = threadIdx.x;
  const int r0 = blockIdx.x * 2;

  const float* Wg[4] = {Wf, Wi, Wc, Wo};
  const float* Bg[4] = {bf, bi, bc, bo};

  // ---- phase 0: stage weights ----
  for (int g = 0; g < 4; ++g) {
    for (int rr = 0; rr < 2; ++rr) {
      const int gr = g * 2 + rr;
      const float* w0 = Wg[g] + (size_t)(r0 + rr) * (En + Hn);
      const float* w1 = Wg[g] + (size_t)(Hn + r0 + rr) * (En + Hn);
      for (int k = tid; k < En + Hn; k += NTHREADS) sW0[gr][k] = w0[k];
      for (int k = tid; k < Hn; k += NTHREADS) sW1[gr][k] = w1[k] + w1[k + Hn];
    }
  }
  if (tid < 16) {
    int l = tid >> 3, gr = tid & 7;
    sBias[l][gr] = Bg[gr >> 1][l * Hn + r0 + (gr & 1)];
  }
  if (tid < 2 * Bn) {
    int rr = tid >> 6, bb = tid & 63;
    h0buf[(r0 + rr) * Bn + bb] = 0.f;
    sC[rr][bb] = 0.f;
  }
  grid_sync(cnt, gen);

  const int gr = tid >> 6;   // 0..7 (wave index)
  const int b  = tid & 63;   // batch column (lane)
  const float* hb0 = h0buf + b;   // read side of phase 0
  const float* hb1 = h1buf + b;   // read side of phase 1

  for (int t = 0; t < Sn; ++t) {
    // ---------- layer 0: a = W0 @ [h(buf0); x_emb] ; writes h -> buf1 ----------
    {
      const int idx = texts[t * Bn + b];
      const float* erow = emb + (size_t)idx * En;
      const float* w = sW0[gr];
      float acc = 0.f;
      #pragma unroll 2
      for (int k = 0; k < Hn; k += 4) {
        float4 wv = *(const float4*)(w + k);
        acc += wv.x * hb0[(k + 0) * Bn];
        acc += wv.y * hb0[(k + 1) * Bn];
        acc += wv.z * hb0[(k + 2) * Bn];
        acc += wv.w * hb0[(k + 3) * Bn];
      }
      #pragma unroll 4
      for (int e = 0; e < En; e += 4) {
        float4 wv = *(const float4*)(w + Hn + e);
        float4 xv = *(const float4*)(erow + e);
        acc += wv.x * xv.x + wv.y * xv.y + wv.z * xv.z + wv.w * xv.w;
      }
      sA[gr][b] = acc;
    }
    __syncthreads();
    if (tid < 2 * Bn) {  // gate update, layer 0 -> write buf1
      int rr = tid >> 6, bb = tid & 63;
      float ft = sigmoidf_(sA[0 + rr][bb] + sBias[0][0 + rr]);
      float it = sigmoidf_(sA[2 + rr][bb] + sBias[0][2 + rr]);
      float ch = tanhf(sA[4 + rr][bb] + sBias[0][4 + rr]);
      float ot = sigmoidf_(sA[6 + rr][bb] + sBias[0][6 + rr]);
      float cn = ft * sC[rr][bb] + it * ch;
      sC[rr][bb] = cn;
      h1buf[(r0 + rr) * Bn + bb] = ot * tanhf(cn);
    }
    grid_sync(cnt, gen);

    // ---------- layer 1: a = W1fold @ h(buf1) ; writes h -> buf0 ----------
    {
      const float* w = sW1[gr];
      float acc = 0.f;
      #pragma unroll 2
      for (int k = 0; k < Hn; k += 4) {
        float4 wv = *(const float4*)(w + k);
        acc += wv.x * hb1[(k + 0) * Bn];
        acc += wv.y * hb1[(k + 1) * Bn];
        acc += wv.z * hb1[(k + 2) * Bn];
        acc += wv.w * hb1[(k + 3) * Bn];
      }
      sA[gr][b] = acc;
    }
    __syncthreads();
    if (tid < 2 * Bn) {  // gate update, layer 1 -> write buf0
      int rr = tid >> 6, bb = tid & 63;
      float ft = sigmoidf_(sA[0 + rr][bb] + sBias[1][0 + rr]);
      float it = sigmoidf_(sA[2 + rr][bb] + sBias[1][2 + rr]);
      float ch = tanhf(sA[4 + rr][bb] + sBias[1][4 + rr]);
      float ot = sigmoidf_(sA[6 + rr][bb] + sBias[1][6 + rr]);
      float cn = ft * sC[rr][bb] + it * ch;
      sC[rr][bb] = cn;
      h0buf[(r0 + rr) * Bn + bb] = ot * tanhf(cn);
    }
    grid_sync(cnt, gen);
  }

  // ---------- epilogue: y[b][o] = sum_r h0[r][b] * Wy[o][r] + by[o] ----------
  if (blockIdx.x == 0 && tid < Bn * OUTn) {
    const int bb = tid >> 1, o = tid & 1;
    float acc = by[o];
    const float* wy = Wy + o * Hn;
    const float* hcol = h0buf + bb;
    for (int r = 0; r < Hn; ++r) acc += hcol[r * Bn] * wy[r];
    out[bb * OUTn + o] = acc;
  }
}

extern "C" void kernel_launch(void* const* d_in, const int* in_sizes, int n_in,
                              void* d_out, int out_size, void* d_ws, size_t ws_size,
                              hipStream_t stream) {
  const int*   texts = (const int*)d_in[0];
  const float* emb   = (const float*)d_in[1];
  const float* Wf    = (const float*)d_in[2];
  const float* bf    = (const float*)d_in[3];
  const float* Wi    = (const float*)d_in[4];
  const float* bi    = (const float*)d_in[5];
  const float* Wo    = (const float*)d_in[6];
  const float* bo    = (const float*)d_in[7];
  const float* Wc    = (const float*)d_in[8];
  const float* bc    = (const float*)d_in[9];
  const float* Wy    = (const float*)d_in[10];
  const float* by    = (const float*)d_in[11];
  float* out = (float*)d_out;

  float* h0buf = (float*)d_ws;                       // 512*64 f32 = 128 KB
  float* h1buf = h0buf + (size_t)Hn * Bn;            // 128 KB
  unsigned* bar = (unsigned*)((char*)d_ws + 2 * (size_t)Hn * Bn * sizeof(float));
  unsigned* cnt = bar;
  unsigned* gen = bar + 1;
  hipMemsetAsync((void*)bar, 0, 2 * sizeof(unsigned), stream);

  void* args[] = {(void*)&texts, (void*)&emb, (void*)&Wf, (void*)&bf, (void*)&Wi, (void*)&bi,
                  (void*)&Wo, (void*)&bo, (void*)&Wc, (void*)&bc, (void*)&Wy, (void*)&by,
                  (void*)&out, (void*)&h0buf, (void*)&h1buf, (void*)&cnt, (void*)&gen};
  hipLaunchCooperativeKernel((const void*)lstm_persistent, dim3(NBLOCKS), dim3(NTHREADS),
                             args, 0, stream);
}

// Round 4
// 14676.320 us; speedup vs baseline: 3.6086x; 3.6086x over previous
//
#include <hip/hip_runtime.h>

// LSTM V=32000 E=512 H=512 OUT=2 L=2 S=512 B=64 — persistent cooperative kernel.
// 256 blocks x 256 threads. 4 independent batch-groups of 64 blocks x 16 batch cols.
// Each block owns 8 h-rows (32 gate-rows/layer, packed [f0..7,i0..7,c0..7,o0..7]).
// Recurrent matmul: v_mfma_f32_16x16x32_f16, A-frags (weights) in LDS (built once),
// B-frags (h) read straight from global in fragment-linear layout (coalesced 16B/lane).
// Layer-1 weights folded (x==h): W@[h;x] = (W[:,:H]+W[:,H:])@h.
// x-projection (emb part, W[:,H:] !, + L0 bias) precomputed per 32-step chunk.

typedef _Float16 f16;
typedef _Float16 f16x8 __attribute__((ext_vector_type(8)));
typedef float f32x4 __attribute__((ext_vector_type(4)));
typedef unsigned int u32;

constexpr int Hn = 512, En = 512, Bn = 64, Sn = 512, OUTn = 2;
constexpr int NB = 256, NT = 256;
constexpr int NG = 4, GB = 64, BS = 16;  // groups, blocks/group, batch cols/group
constexpr int RPB = 8;                   // h-rows per block
constexpr int CH = 32;                   // chunk length (steps) for x-projection

// ws layout (bytes)
constexpr size_t XP_OFF = 0;                                   // f16 Xp[NG*GB][CH][32][16] = 8 MB
constexpr size_t XP_SZ  = (size_t)NG * GB * CH * 32 * 16 * 2;
constexpr size_t HB_OFF = XP_SZ;                                // f16 hb[NG][2] buffers, 16 KB each
constexpr size_t HB_SZ  = (size_t)NG * 2 * (Hn / 32) * 64 * 16;
constexpr size_t BAR_OFF = XP_OFF + XP_SZ + HB_SZ;
constexpr size_t BAR_SZ = NG * 256;

__device__ __forceinline__ void gbar(u32* cnt, u32* gen) {
  __syncthreads();
  if (threadIdx.x == 0) {
    __threadfence();
    u32 g = __hip_atomic_load(gen, __ATOMIC_RELAXED, __HIP_MEMORY_SCOPE_AGENT);
    u32 a = __hip_atomic_fetch_add(cnt, 1u, __ATOMIC_ACQ_REL, __HIP_MEMORY_SCOPE_AGENT);
    if (a == GB - 1) {
      __hip_atomic_store(cnt, 0u, __ATOMIC_RELAXED, __HIP_MEMORY_SCOPE_AGENT);
      __hip_atomic_store(gen, g + 1u, __ATOMIC_RELEASE, __HIP_MEMORY_SCOPE_AGENT);
    } else {
      while (__hip_atomic_load(gen, __ATOMIC_RELAXED, __HIP_MEMORY_SCOPE_AGENT) == g)
        __builtin_amdgcn_s_sleep(1);
    }
    __threadfence();
  }
  __syncthreads();
}

__device__ __forceinline__ float sig_(float x) { return 1.f / (1.f + expf(-x)); }

// fragment-linear element index for (k, col) in a 512xBS f16 buffer (BS=16):
// slot = (k>>5)*64 + ((k>>3)&3)*16 + col ; elem = slot*8 + (k&7)
__device__ __forceinline__ int fl_idx(int k, int col) {
  return (((k >> 5) * 64 + (((k >> 3) & 3) * 16) + col) << 3) + (k & 7);
}

__global__ void __launch_bounds__(NT) lstm_mfma(
    const int* __restrict__ texts, const float* __restrict__ emb,
    const float* __restrict__ Wf, const float* __restrict__ bf,
    const float* __restrict__ Wi, const float* __restrict__ bi,
    const float* __restrict__ Wo, const float* __restrict__ bo,
    const float* __restrict__ Wc, const float* __restrict__ bc,
    const float* __restrict__ Wy, const float* __restrict__ by,
    float* __restrict__ out, f16* __restrict__ Xp, char* __restrict__ hbBase,
    u32* __restrict__ barBase)
{
  __shared__ f16x8 sWA[2][2][16][64];   // [layer][mtile][kstep][lane] recurrent A-frags, 64 KB
  __shared__ f16x8 sWAX[2][16][64];     // [mtile][kstep][lane] layer-0 x-part A-frags, 32 KB
  __shared__ f16x8 sBX[2][16][64];      // xproj B-frags for 2 steps, 32 KB
  __shared__ float sAcc[2][32][17];     // [khalf][row][col pad]
  __shared__ float sBias1[32], sBiasX[32];
  __shared__ float sC[RPB][BS];
  __shared__ float sRed[BS][OUTn][8];

  const int tid = threadIdx.x;
  const int bid = blockIdx.x;
  const int g = (bid & 7) >> 1;                    // group (XCD-pair locality)
  const int rank = ((bid >> 3) << 1) | (bid & 1);  // 0..63 within group
  const int w = tid >> 6, l = tid & 63;

  const float* Wg[4] = {Wf, Wi, Wc, Wo};
  const float* Bg[4] = {bf, bi, bc, bo};

  f16* hb0 = (f16*)(hbBase + (size_t)(g * 2 + 0) * 16384);
  f16* hb1 = (f16*)(hbBase + (size_t)(g * 2 + 1) * 16384);
  u32* cnt = barBase + g * 64;        // 256B stride per group
  u32* gen = barBase + g * 64 + 32;
  f16* XpMine = Xp + ((size_t)(g * GB + rank) * CH) * 512;

  // ---- prologue: build A-frags (f16) in LDS ----
  // recurrent parts: layer0 = W[:, 0:H], layer1 folded = W[:, 0:H] + W[:, H:2H]
  for (int i = 0; i < 16; ++i) {
    int slot = tid * 16 + i;            // 4096 slots
    int sl = slot & 63, s = (slot >> 6) & 15, mt = (slot >> 10) & 1, L = (slot >> 11) & 1;
    int m = sl & 15, kg = sl >> 4;
    int r = mt * 16 + m;                // packed row 0..31
    int gate = r >> 3, hr = r & 7;
    const float* row = Wg[gate] + ((size_t)L * Hn + rank * RPB + hr) * (En + Hn);
    int k0 = s * 32 + kg * 8;
    f16x8 v;
    #pragma unroll
    for (int j = 0; j < 8; ++j) {
      float x = row[k0 + j];
      if (L == 1) x += row[k0 + j + Hn];
      v[j] = (f16)x;
    }
    sWA[L][mt][s][sl] = v;
  }
  // layer-0 x-part: W[:, H:H+E]  (THE round-3 bugfix)
  for (int i = 0; i < 8; ++i) {
    int slot = tid * 8 + i;             // 2048 slots
    int sl = slot & 63, s = (slot >> 6) & 15, mt = (slot >> 10) & 1;
    int m = sl & 15, kg = sl >> 4;
    int r = mt * 16 + m;
    int gate = r >> 3, hr = r & 7;
    const float* row = Wg[gate] + (size_t)(rank * RPB + hr) * (En + Hn);
    int k0 = Hn + s * 32 + kg * 8;
    f16x8 v;
    #pragma unroll
    for (int j = 0; j < 8; ++j) v[j] = (f16)row[k0 + j];
    sWAX[mt][s][sl] = v;
  }
  if (tid < 32) {
    int gate = tid >> 3, hr = tid & 7;
    sBiasX[tid] = Bg[gate][0 * Hn + rank * RPB + hr];
    sBias1[tid] = Bg[gate][1 * Hn + rank * RPB + hr];
  }
  if (tid < RPB * BS) sC[tid >> 4][tid & 15] = 0.f;
  // zero h buffer 0 (every block zeros the whole buffer; identical values — benign)
  for (int i = tid; i < 16384 / 4; i += NT) ((u32*)hb0)[i] = 0u;

  const int mt = w & 1, kh = w >> 1;
  const int col = l & 15, rbase0 = (l >> 4) << 2;

  for (int t = 0; t < Sn; ++t) {
    // ---- chunk refill: x-projection for t..t+31 (block-local, no grid barrier) ----
    if ((t & (CH - 1)) == 0) {
      for (int tp = 0; tp < CH / 2; ++tp) {
        {  // stage two steps' x into B-frags (gather + f32->f16)
          int tsel = tid >> 7, b = (tid >> 3) & 15, kc = tid & 7;
          int tt = t + tp * 2 + tsel;
          int idx = texts[tt * Bn + g * BS + b];
          const float* er = emb + (size_t)idx * En + kc * 64;
          #pragma unroll
          for (int half = 0; half < 2; ++half) {
            int s = kc * 2 + half;
            #pragma unroll
            for (int kg = 0; kg < 4; ++kg) {
              f16x8 v;
              #pragma unroll
              for (int j = 0; j < 8; ++j) v[j] = (f16)er[half * 32 + kg * 8 + j];
              sBX[tsel][s][kg * 16 + b] = v;
            }
          }
        }
        __syncthreads();
        {  // MFMA with x-part weights: wave = (mtile, tsel)
          int ts = kh;
          f32x4 acc = {0.f, 0.f, 0.f, 0.f};
          #pragma unroll
          for (int s = 0; s < 16; ++s)
            acc = __builtin_amdgcn_mfma_f32_16x16x32_f16(sWAX[mt][s][l], sBX[ts][s][l], acc, 0, 0, 0);
          int t32 = tp * 2 + ts;
          f16* dst = XpMine + (size_t)t32 * 512;
          #pragma unroll
          for (int v = 0; v < 4; ++v) {
            int r = mt * 16 + rbase0 + v;
            dst[r * 16 + col] = (f16)(acc[v] + sBiasX[r]);
          }
        }
        __syncthreads();
      }
    }

    // ---- phase A: layer 0 (read hb0, write hb1) ----
    {
      const f16x8* hbR = (const f16x8*)hb0;
      f16x8 bfrag[8];
      #pragma unroll
      for (int i = 0; i < 8; ++i) bfrag[i] = hbR[(kh * 8 + i) * 64 + l];
      f32x4 acc = {0.f, 0.f, 0.f, 0.f};
      #pragma unroll
      for (int i = 0; i < 8; ++i)
        acc = __builtin_amdgcn_mfma_f32_16x16x32_f16(sWA[0][mt][kh * 8 + i][l], bfrag[i], acc, 0, 0, 0);
      #pragma unroll
      for (int v = 0; v < 4; ++v) sAcc[kh][mt * 16 + rbase0 + v][col] = acc[v];
    }
    __syncthreads();
    if (tid < RPB * BS) {
      int hr = tid >> 4, b = tid & 15;
      const f16* xp = XpMine + (size_t)(t & (CH - 1)) * 512;
      float af = sAcc[0][0 + hr][b] + sAcc[1][0 + hr][b] + (float)xp[(0 + hr) * 16 + b];
      float ai = sAcc[0][8 + hr][b] + sAcc[1][8 + hr][b] + (float)xp[(8 + hr) * 16 + b];
      float ac = sAcc[0][16 + hr][b] + sAcc[1][16 + hr][b] + (float)xp[(16 + hr) * 16 + b];
      float ao = sAcc[0][24 + hr][b] + sAcc[1][24 + hr][b] + (float)xp[(24 + hr) * 16 + b];
      float ft = sig_(af), it = sig_(ai), ch = tanhf(ac), ot = sig_(ao);
      float c = ft * sC[hr][b] + it * ch;
      sC[hr][b] = c;
      hb1[fl_idx(rank * RPB + hr, b)] = (f16)(ot * tanhf(c));
    }
    gbar(cnt, gen);

    // ---- phase B: layer 1 folded (read hb1, write hb0) ----
    {
      const f16x8* hbR = (const f16x8*)hb1;
      f16x8 bfrag[8];
      #pragma unroll
      for (int i = 0; i < 8; ++i) bfrag[i] = hbR[(kh * 8 + i) * 64 + l];
      f32x4 acc = {0.f, 0.f, 0.f, 0.f};
      #pragma unroll
      for (int i = 0; i < 8; ++i)
        acc = __builtin_amdgcn_mfma_f32_16x16x32_f16(sWA[1][mt][kh * 8 + i][l], bfrag[i], acc, 0, 0, 0);
      #pragma unroll
      for (int v = 0; v < 4; ++v) sAcc[kh][mt * 16 + rbase0 + v][col] = acc[v];
    }
    __syncthreads();
    if (tid < RPB * BS) {
      int hr = tid >> 4, b = tid & 15;
      float af = sAcc[0][0 + hr][b] + sAcc[1][0 + hr][b] + sBias1[0 + hr];
      float ai = sAcc[0][8 + hr][b] + sAcc[1][8 + hr][b] + sBias1[8 + hr];
      float ac = sAcc[0][16 + hr][b] + sAcc[1][16 + hr][b] + sBias1[16 + hr];
      float ao = sAcc[0][24 + hr][b] + sAcc[1][24 + hr][b] + sBias1[24 + hr];
      float ft = sig_(af), it = sig_(ai), ch = tanhf(ac), ot = sig_(ao);
      float c = ft * sC[hr][b] + it * ch;
      sC[hr][b] = c;
      hb0[fl_idx(rank * RPB + hr, b)] = (f16)(ot * tanhf(c));
    }
    gbar(cnt, gen);
  }

  // ---- epilogue: y[b][o] = h^T Wy^T + by (rank 0 of each group, its 16 cols) ----
  if (rank == 0) {
    int kc = tid & 7, o = (tid >> 3) & 1, b = tid >> 4;  // 8 x 2 x 16
    float p = 0.f;
    for (int kk = 0; kk < 64; ++kk) {
      int k = kc * 64 + kk;
      p += (float)hb0[fl_idx(k, b)] * Wy[o * Hn + k];
    }
    sRed[b][o][kc] = p;
    __syncthreads();
    if (tid < BS * OUTn) {
      int b2 = tid >> 1, o2 = tid & 1;
      float s = by[o2];
      #pragma unroll
      for (int q = 0; q < 8; ++q) s += sRed[b2][o2][q];
      out[(g * BS + b2) * OUTn + o2] = s;
    }
  }
}

extern "C" void kernel_launch(void* const* d_in, const int* in_sizes, int n_in,
                              void* d_out, int out_size, void* d_ws, size_t ws_size,
                              hipStream_t stream) {
  const int*   texts = (const int*)d_in[0];
  const float* emb   = (const float*)d_in[1];
  const float* Wf    = (const float*)d_in[2];
  const float* bf    = (const float*)d_in[3];
  const float* Wi    = (const float*)d_in[4];
  const float* bi    = (const float*)d_in[5];
  const float* Wo    = (const float*)d_in[6];
  const float* bo    = (const float*)d_in[7];
  const float* Wc    = (const float*)d_in[8];
  const float* bc    = (const float*)d_in[9];
  const float* Wy    = (const float*)d_in[10];
  const float* by    = (const float*)d_in[11];
  float* out = (float*)d_out;

  f16*  Xp      = (f16*)((char*)d_ws + XP_OFF);
  char* hbBase  = (char*)d_ws + HB_OFF;
  u32*  barBase = (u32*)((char*)d_ws + BAR_OFF);
  hipMemsetAsync((void*)barBase, 0, BAR_SZ, stream);

  void* args[] = {(void*)&texts, (void*)&emb, (void*)&Wf, (void*)&bf, (void*)&Wi, (void*)&bi,
                  (void*)&Wo, (void*)&bo, (void*)&Wc, (void*)&bc, (void*)&Wy, (void*)&by,
                  (void*)&out, (void*)&Xp, (void*)&hbBase, (void*)&barBase};
  hipLaunchCooperativeKernel((const void*)lstm_mfma, dim3(NB), dim3(NT), args, 0, stream);
}

// Round 5
// 10500.465 us; speedup vs baseline: 5.0436x; 1.3977x over previous
//
#include <hip/hip_runtime.h>

// LSTM V=32000 E=512 H=512 OUT=2 L=2 S=512 B=64 — persistent cooperative kernel.
// 256 blocks x 256 threads. 4 independent batch-groups of 64 blocks x 16 batch cols.
// Each block owns 8 h-rows (32 gate-rows/layer, packed [f,i,c,o] x 8).
// Recurrent matmul: v_mfma_f32_16x16x32_f16; recurrent A-frags in LDS; B-frags (h)
// read from global in fragment-linear layout. Layer-1 folded: W@[h;h]=(Wh+Wx)@h.
// R5: flag-array grid barrier (no atomic RMW serialization) + x-projection slices
// computed inside the barrier wait window (LDS double-buffered, CH=16); layer-0
// x-part weights fragment-packed to global f16 by a pre-pass kernel.

typedef _Float16 f16;
typedef _Float16 f16x8 __attribute__((ext_vector_type(8)));
typedef float f32x4 __attribute__((ext_vector_type(4)));
typedef unsigned int u32;

constexpr int Hn = 512, En = 512, Bn = 64, Sn = 512, OUTn = 2;
constexpr int NB = 256, NT = 256;
constexpr int NG = 4, GB = 64, BS = 16;  // groups, blocks/group, batch cols/group
constexpr int RPB = 8;                   // h-rows per block
constexpr int CH = 16;                   // xp chunk length (steps)

// ws layout (bytes)
constexpr size_t WXF_OFF = 0;                                   // f16x8 W_xf[64 ranks][2][16][64]
constexpr size_t WXF_SZ  = (size_t)GB * 2 * 16 * 64 * 16;       // 2 MB
constexpr size_t HB_OFF  = WXF_OFF + WXF_SZ;                    // f16 hb[NG][2] 16 KB bufs
constexpr size_t HB_SZ   = (size_t)NG * 2 * 16384;              // 128 KB
constexpr size_t FLAG_OFF = HB_OFF + HB_SZ;                     // u32 flags, 256B/rank
constexpr size_t FLAG_SZ  = (size_t)NG * GB * 256;              // 64 KB

__device__ __forceinline__ float sig_(float x) { return 1.f / (1.f + expf(-x)); }

// fragment-linear element index for (k, col) in a 512xBS f16 buffer (BS=16)
__device__ __forceinline__ int fl_idx(int k, int col) {
  return (((k >> 5) * 64 + (((k >> 3) & 3) * 16) + col) << 3) + (k & 7);
}

// -------- pre-pass: fragment-pack layer-0 x-part weights (W[:, H:H+E]) to f16 --------
__global__ void __launch_bounds__(256) prepack_wxf(
    const float* __restrict__ Wf, const float* __restrict__ Wi,
    const float* __restrict__ Wo, const float* __restrict__ Wc,
    f16x8* __restrict__ W_xf)
{
  const float* Wg[4] = {Wf, Wi, Wc, Wo};
  const int rank = blockIdx.x, tid = threadIdx.x;
  for (int i = 0; i < 8; ++i) {
    int slot = tid * 8 + i;                 // 2048 slots per rank
    int sl = slot & 63, s = (slot >> 6) & 15, mt = (slot >> 10) & 1;
    int m = sl & 15, kg = sl >> 4;
    int r = mt * 16 + m, gate = r >> 3, hr = r & 7;
    const float* row = Wg[gate] + (size_t)(rank * RPB + hr) * (En + Hn);
    int k0 = Hn + s * 32 + kg * 8;
    f16x8 v;
    #pragma unroll
    for (int j = 0; j < 8; ++j) v[j] = (f16)row[k0 + j];
    W_xf[((size_t)(rank * 2 + mt) * 16 + s) * 64 + sl] = v;
  }
}

__global__ void __launch_bounds__(NT) lstm_mfma(
    const int* __restrict__ texts, const float* __restrict__ emb,
    const float* __restrict__ Wf, const float* __restrict__ bf,
    const float* __restrict__ Wi, const float* __restrict__ bi,
    const float* __restrict__ Wo, const float* __restrict__ bo,
    const float* __restrict__ Wc, const float* __restrict__ bc,
    const float* __restrict__ Wy, const float* __restrict__ by,
    float* __restrict__ out, const f16x8* __restrict__ W_xf,
    char* __restrict__ hbBase, u32* __restrict__ flagBase)
{
  __shared__ f16x8 sWA[2][2][16][64];   // recurrent A-frags, 64 KB
  __shared__ f16x8 sBX[2][16][64];      // xp staging B-frags (2 steps), 32 KB
  __shared__ f16   sXp[2][CH][32][16];  // xp double buffer, 32 KB
  __shared__ float sAcc[2][32][17];
  __shared__ float sBias1[32], sBiasX[32];
  __shared__ float sC[RPB][BS];
  __shared__ float sRed[BS][OUTn][8];

  const int tid = threadIdx.x;
  const int bid = blockIdx.x;
  const int g = (bid & 7) >> 1;                    // group (XCD-pair locality)
  const int rank = ((bid >> 3) << 1) | (bid & 1);  // 0..63 within group
  const int w = tid >> 6, l = tid & 63;

  const float* Wg[4] = {Wf, Wi, Wc, Wo};
  const float* Bg[4] = {bf, bi, bc, bo};

  f16* hb0 = (f16*)(hbBase + (size_t)(g * 2 + 0) * 16384);
  f16* hb1 = (f16*)(hbBase + (size_t)(g * 2 + 1) * 16384);
  u32* flagG  = flagBase + (size_t)g * GB * 64;    // 64 u32 (256B) per rank
  u32* myFlag = flagG + (size_t)rank * 64;

  // ---- prologue: recurrent A-frags (L0 = W[:, :H]; L1 folded = W[:, :H]+W[:, H:]) ----
  for (int i = 0; i < 16; ++i) {
    int slot = tid * 16 + i;            // 4096 slots
    int sl = slot & 63, s = (slot >> 6) & 15, mt = (slot >> 10) & 1, L = (slot >> 11) & 1;
    int m = sl & 15, kg = sl >> 4;
    int r = mt * 16 + m, gate = r >> 3, hr = r & 7;
    const float* row = Wg[gate] + ((size_t)L * Hn + rank * RPB + hr) * (En + Hn);
    int k0 = s * 32 + kg * 8;
    f16x8 v;
    #pragma unroll
    for (int j = 0; j < 8; ++j) {
      float x = row[k0 + j];
      if (L == 1) x += row[k0 + j + Hn];
      v[j] = (f16)x;
    }
    sWA[L][mt][s][sl] = v;
  }
  if (tid < 32) {
    int gate = tid >> 3, hr = tid & 7;
    sBiasX[tid] = Bg[gate][0 * Hn + rank * RPB + hr];
    sBias1[tid] = Bg[gate][1 * Hn + rank * RPB + hr];
  }
  if (tid < RPB * BS) sC[tid >> 4][tid & 15] = 0.f;
  for (int i = tid; i < 16384 / 4; i += NT) ((u32*)hb0)[i] = 0u;

  const int mt = w & 1, kh = w >> 1;
  const int col = l & 15, rbase0 = (l >> 4) << 2;

  // xp slice: compute x-projection (+L0 bias) for steps tb, tb+1 into sXp
  auto do_slice = [&](int tb) {
    {  // stage x for 2 steps (gather emb, f32->f16)
      int tsel = tid >> 7, b = (tid >> 3) & 15, kc = tid & 7;
      int tt = tb + tsel;
      int idx = texts[tt * Bn + g * BS + b];
      const float* er = emb + (size_t)idx * En + kc * 64;
      #pragma unroll
      for (int half = 0; half < 2; ++half) {
        int s = kc * 2 + half;
        #pragma unroll
        for (int kg = 0; kg < 4; ++kg) {
          f16x8 v;
          #pragma unroll
          for (int j = 0; j < 8; ++j) v[j] = (f16)er[half * 32 + kg * 8 + j];
          sBX[tsel][s][kg * 16 + b] = v;
        }
      }
    }
    __syncthreads();
    {  // MFMA: wave = (mtile mt, step-sel kh); A from global W_xf (coalesced 16B/lane)
      int ts = kh;
      const f16x8* wx = W_xf + ((size_t)(rank * 2 + mt) * 16) * 64;
      f32x4 acc = {0.f, 0.f, 0.f, 0.f};
      #pragma unroll
      for (int s = 0; s < 16; ++s)
        acc = __builtin_amdgcn_mfma_f32_16x16x32_f16(wx[s * 64 + l], sBX[ts][s][l], acc, 0, 0, 0);
      int t32 = tb + ts;
      #pragma unroll
      for (int v = 0; v < 4; ++v) {
        int r = mt * 16 + rbase0 + v;
        sXp[(t32 >> 4) & 1][t32 & 15][r][col] = (f16)(acc[v] + sBiasX[r]);
      }
    }
  };

  // chunk 0 synchronously
  for (int tp = 0; tp < CH / 2; ++tp) { do_slice(tp * 2); __syncthreads(); }

  u32 phase = 0;

  // initial barrier (publishes zeroed hb0)
  __syncthreads();
  ++phase;
  if (tid == 0) { __threadfence();
    __hip_atomic_store(myFlag, phase, __ATOMIC_RELAXED, __HIP_MEMORY_SCOPE_AGENT); }
  if (tid < 64) {
    u32* fp = flagG + (size_t)l * 64;
    u32 v = __hip_atomic_load(fp, __ATOMIC_RELAXED, __HIP_MEMORY_SCOPE_AGENT);
    while (__any(v < phase)) { __builtin_amdgcn_s_sleep(1);
      v = __hip_atomic_load(fp, __ATOMIC_RELAXED, __HIP_MEMORY_SCOPE_AGENT); }
    __threadfence();
  }
  __syncthreads();

  for (int t = 0; t < Sn; ++t) {
    // ---------- phase A: layer 0 (read hb0, write hb1) ----------
    {
      const f16x8* hbR = (const f16x8*)hb0;
      f16x8 bfrag[8];
      #pragma unroll
      for (int i = 0; i < 8; ++i) bfrag[i] = hbR[(kh * 8 + i) * 64 + l];
      f32x4 acc = {0.f, 0.f, 0.f, 0.f};
      #pragma unroll
      for (int i = 0; i < 8; ++i)
        acc = __builtin_amdgcn_mfma_f32_16x16x32_f16(sWA[0][mt][kh * 8 + i][l], bfrag[i], acc, 0, 0, 0);
      #pragma unroll
      for (int v = 0; v < 4; ++v) sAcc[kh][mt * 16 + rbase0 + v][col] = acc[v];
    }
    __syncthreads();
    if (tid < RPB * BS) {
      int hr = tid >> 4, b = tid & 15;
      const f16 (*xp)[16] = sXp[(t >> 4) & 1][t & 15];
      float af = sAcc[0][0 + hr][b] + sAcc[1][0 + hr][b] + (float)xp[0 + hr][b];
      float ai = sAcc[0][8 + hr][b] + sAcc[1][8 + hr][b] + (float)xp[8 + hr][b];
      float ac = sAcc[0][16 + hr][b] + sAcc[1][16 + hr][b] + (float)xp[16 + hr][b];
      float ao = sAcc[0][24 + hr][b] + sAcc[1][24 + hr][b] + (float)xp[24 + hr][b];
      float ft = sig_(af), it = sig_(ai), ch = tanhf(ac), ot = sig_(ao);
      float c = ft * sC[hr][b] + it * ch;
      sC[hr][b] = c;
      hb1[fl_idx(rank * RPB + hr, b)] = (f16)(ot * tanhf(c));
    }
    __syncthreads();
    ++phase;
    if (tid == 0) { __threadfence();
      __hip_atomic_store(myFlag, phase, __ATOMIC_RELAXED, __HIP_MEMORY_SCOPE_AGENT); }
    // hide next chunk's xp slice in the barrier window (8 slices per 16-step chunk)
    if ((t & 1) == 0 && (t >> 4) < (Sn / CH) - 1)
      do_slice((((t >> 4) + 1) << 4) + (t & 15));
    if (tid < 64) {
      u32* fp = flagG + (size_t)l * 64;
      u32 v = __hip_atomic_load(fp, __ATOMIC_RELAXED, __HIP_MEMORY_SCOPE_AGENT);
      while (__any(v < phase)) { __builtin_amdgcn_s_sleep(1);
        v = __hip_atomic_load(fp, __ATOMIC_RELAXED, __HIP_MEMORY_SCOPE_AGENT); }
      __threadfence();
    }
    __syncthreads();

    // ---------- phase B: layer 1 folded (read hb1, write hb0) ----------
    {
      const f16x8* hbR = (const f16x8*)hb1;
      f16x8 bfrag[8];
      #pragma unroll
      for (int i = 0; i < 8; ++i) bfrag[i] = hbR[(kh * 8 + i) * 64 + l];
      f32x4 acc = {0.f, 0.f, 0.f, 0.f};
      #pragma unroll
      for (int i = 0; i < 8; ++i)
        acc = __builtin_amdgcn_mfma_f32_16x16x32_f16(sWA[1][mt][kh * 8 + i][l], bfrag[i], acc, 0, 0, 0);
      #pragma unroll
      for (int v = 0; v < 4; ++v) sAcc[kh][mt * 16 + rbase0 + v][col] = acc[v];
    }
    __syncthreads();
    if (tid < RPB * BS) {
      int hr = tid >> 4, b = tid & 15;
      float af = sAcc[0][0 + hr][b] + sAcc[1][0 + hr][b] + sBias1[0 + hr];
      float ai = sAcc[0][8 + hr][b] + sAcc[1][8 + hr][b] + sBias1[8 + hr];
      float ac = sAcc[0][16 + hr][b] + sAcc[1][16 + hr][b] + sBias1[16 + hr];
      float ao = sAcc[0][24 + hr][b] + sAcc[1][24 + hr][b] + sBias1[24 + hr];
      float ft = sig_(af), it = sig_(ai), ch = tanhf(ac), ot = sig_(ao);
      float c = ft * sC[hr][b] + it * ch;
      sC[hr][b] = c;
      hb0[fl_idx(rank * RPB + hr, b)] = (f16)(ot * tanhf(c));
    }
    __syncthreads();
    ++phase;
    if (tid == 0) { __threadfence();
      __hip_atomic_store(myFlag, phase, __ATOMIC_RELAXED, __HIP_MEMORY_SCOPE_AGENT); }
    if (tid < 64) {
      u32* fp = flagG + (size_t)l * 64;
      u32 v = __hip_atomic_load(fp, __ATOMIC_RELAXED, __HIP_MEMORY_SCOPE_AGENT);
      while (__any(v < phase)) { __builtin_amdgcn_s_sleep(1);
        v = __hip_atomic_load(fp, __ATOMIC_RELAXED, __HIP_MEMORY_SCOPE_AGENT); }
      __threadfence();
    }
    __syncthreads();
  }

  // ---------- epilogue: y = h^T Wy^T + by (rank 0 of each group) ----------
  if (rank == 0) {
    int kc = tid & 7, o = (tid >> 3) & 1, b = tid >> 4;  // 8 x 2 x 16
    float p = 0.f;
    for (int kk = 0; kk < 64; ++kk) {
      int k = kc * 64 + kk;
      p += (float)hb0[fl_idx(k, b)] * Wy[o * Hn + k];
    }
    sRed[b][o][kc] = p;
    __syncthreads();
    if (tid < BS * OUTn) {
      int b2 = tid >> 1, o2 = tid & 1;
      float s = by[o2];
      #pragma unroll
      for (int q = 0; q < 8; ++q) s += sRed[b2][o2][q];
      out[(g * BS + b2) * OUTn + o2] = s;
    }
  }
}

extern "C" void kernel_launch(void* const* d_in, const int* in_sizes, int n_in,
                              void* d_out, int out_size, void* d_ws, size_t ws_size,
                              hipStream_t stream) {
  const int*   texts = (const int*)d_in[0];
  const float* emb   = (const float*)d_in[1];
  const float* Wf    = (const float*)d_in[2];
  const float* bf    = (const float*)d_in[3];
  const float* Wi    = (const float*)d_in[4];
  const float* bi    = (const float*)d_in[5];
  const float* Wo    = (const float*)d_in[6];
  const float* bo    = (const float*)d_in[7];
  const float* Wc    = (const float*)d_in[8];
  const float* bc    = (const float*)d_in[9];
  const float* Wy    = (const float*)d_in[10];
  const float* by    = (const float*)d_in[11];
  float* out = (float*)d_out;

  f16x8* W_xf    = (f16x8*)((char*)d_ws + WXF_OFF);
  char*  hbBase  = (char*)d_ws + HB_OFF;
  u32*   flagBase = (u32*)((char*)d_ws + FLAG_OFF);
  hipMemsetAsync((void*)flagBase, 0, FLAG_SZ, stream);

  prepack_wxf<<<dim3(GB), dim3(256), 0, stream>>>(Wf, Wi, Wo, Wc, W_xf);

  void* args[] = {(void*)&texts, (void*)&emb, (void*)&Wf, (void*)&bf, (void*)&Wi, (void*)&bi,
                  (void*)&Wo, (void*)&bo, (void*)&Wc, (void*)&bc, (void*)&Wy, (void*)&by,
                  (void*)&out, (void*)&W_xf, (void*)&hbBase, (void*)&flagBase};
  hipLaunchCooperativeKernel((const void*)lstm_mfma, dim3(NB), dim3(NT), args, 0, stream);
}

// Round 6
// 4376.673 us; speedup vs baseline: 12.1006x; 2.3992x over previous
//
#include <hip/hip_runtime.h>

// LSTM V=32000 E=512 H=512 OUT=2 L=2 S=512 B=64 — persistent cooperative kernel.
// 256 blocks x 256 threads. 4 batch-groups of 64 blocks x 16 batch cols.
// Block owns 8 h-rows (32 gate-rows/layer, packed [f,i,c,o] x 8).
// R6: fence-free cross-block protocol — h and flags exchanged via RELAXED
// agent-scope atomics (coherent, bypass stale caches); ordering from the
// vmcnt-drain in __syncthreads + poll control dependency. Dense 4B-stride
// flags (4 lines/group). x-projection folded into phase-A MFMA as K=512..1023
// with B-frags from a pre-pass gather kernel (xb, fragment-linear f16).
// Layer-1 folded: W@[h;h] = (W[:,:H]+W[:,H:])@h.

typedef _Float16 f16;
typedef _Float16 f16x8 __attribute__((ext_vector_type(8)));
typedef float f32x4 __attribute__((ext_vector_type(4)));
typedef unsigned int u32;
typedef unsigned short u16;

constexpr int Hn = 512, En = 512, Bn = 64, Sn = 512, OUTn = 2;
constexpr int NB = 256, NT = 256;
constexpr int NG = 4, GB = 64, BS = 16;  // groups, blocks/group, batch cols/group
constexpr int RPB = 8;                   // h-rows per block

// ws layout (bytes)
constexpr size_t XB_OFF = 0;                                 // f16x8 xb[NG][Sn][16][64] = 32 MB
constexpr size_t XB_SZ  = (size_t)NG * Sn * 16 * 64 * 16;
constexpr size_t HB_OFF = XB_OFF + XB_SZ;                    // f16 hb[NG][2], 16 KB each
constexpr size_t HB_SZ  = (size_t)NG * 2 * 16384;
constexpr size_t FLAG_OFF = HB_OFF + HB_SZ;                  // u32 flags, dense, 4 KB/group
constexpr size_t FLAG_SZ  = (size_t)NG * 4096;

__device__ __forceinline__ float sig_(float x) { return 1.f / (1.f + expf(-x)); }

__device__ __forceinline__ u32 aload(const u32* p) {
  return __hip_atomic_load(p, __ATOMIC_RELAXED, __HIP_MEMORY_SCOPE_AGENT);
}
__device__ __forceinline__ void astore(u32* p, u32 v) {
  __hip_atomic_store(p, v, __ATOMIC_RELAXED, __HIP_MEMORY_SCOPE_AGENT);
}

union uf16x8 { f16x8 v; u32 d[4]; };
union uf16   { f16 f; u16 u; };

// coherent 16B fragment load (4 relaxed agent dwords; compiler tracks waitcnt)
__device__ __forceinline__ f16x8 ldfrag(const u32* base, int frag) {
  uf16x8 u;
  const u32* p = base + frag * 4;
  u.d[0] = aload(p); u.d[1] = aload(p + 1); u.d[2] = aload(p + 2); u.d[3] = aload(p + 3);
  return u.v;
}

// fragment-linear f16-element index for (k, col), BS=16 cols
__device__ __forceinline__ int fl_idx(int k, int col) {
  return (((k >> 5) * 64 + (((k >> 3) & 3) * 16) + col) << 3) + (k & 7);
}

// -------- pre-pass: gather emb -> fragment-linear f16 xb[g][t] --------
__global__ void __launch_bounds__(256) xb_fill(
    const int* __restrict__ texts, const float* __restrict__ emb,
    f16x8* __restrict__ xb)
{
  const int bidx = blockIdx.x;        // g*Sn + t
  const int g = bidx >> 9, t = bidx & (Sn - 1);
  const int tid = threadIdx.x;
  f16x8* dst = xb + (size_t)bidx * 1024;
  for (int slot = tid; slot < 1024; slot += 256) {
    int s = slot >> 6, sl = slot & 63, kg = sl >> 4, b = sl & 15;
    int idx = texts[t * Bn + g * BS + b];
    const float* er = emb + (size_t)idx * En + s * 32 + kg * 8;
    f16x8 v;
    #pragma unroll
    for (int j = 0; j < 8; ++j) v[j] = (f16)er[j];
    dst[slot] = v;
  }
}

__global__ void __launch_bounds__(NT) lstm_mfma(
    const int* __restrict__ texts, const float* __restrict__ emb,
    const float* __restrict__ Wf, const float* __restrict__ bf,
    const float* __restrict__ Wi, const float* __restrict__ bi,
    const float* __restrict__ Wo, const float* __restrict__ bo,
    const float* __restrict__ Wc, const float* __restrict__ bc,
    const float* __restrict__ Wy, const float* __restrict__ by,
    float* __restrict__ out, const f16x8* __restrict__ xb,
    char* __restrict__ hbBase, u32* __restrict__ flagBase)
{
  __shared__ f16x8 sWA0[2][32][64];   // L0 A-frags, K=1024 ([h|x] cat order), 64 KB
  __shared__ f16x8 sWA1[2][16][64];   // L1 folded A-frags, K=512, 32 KB
  __shared__ float sAcc[2][32][17];
  __shared__ float sBiasX[32], sBias1[32];
  __shared__ float sC[RPB][BS];
  __shared__ f16   sH[RPB][BS];
  __shared__ float sRed[BS][OUTn][8];

  const int tid = threadIdx.x;
  const int bid = blockIdx.x;
  const int g = (bid & 7) >> 1;                    // group (XCD-pair locality)
  const int rank = ((bid >> 3) << 1) | (bid & 1);  // 0..63 within group
  const int w = tid >> 6, l = tid & 63;

  const float* Wg[4] = {Wf, Wi, Wc, Wo};
  const float* Bg[4] = {bf, bi, bc, bo};

  u32* hb0 = (u32*)(hbBase + (size_t)(g * 2 + 0) * 16384);
  u32* hb1 = (u32*)(hbBase + (size_t)(g * 2 + 1) * 16384);
  u32* flagG  = flagBase + (size_t)g * 1024;       // dense: rank r at flagG[r]
  u32* myFlag = flagG + rank;

  // ---- prologue: A-frags in LDS ----
  // L0: full 1024-wide rows of W (cat=[h;x] order matches row layout directly)
  for (int i = 0; i < 16; ++i) {
    int slot = tid * 16 + i;            // 4096 slots: [mt][s<32][sl]
    int sl = slot & 63, s = (slot >> 6) & 31, mt = (slot >> 11) & 1;
    int m = sl & 15, kg = sl >> 4;
    int r = mt * 16 + m, gate = r >> 3, hr = r & 7;
    const float* row = Wg[gate] + (size_t)(rank * RPB + hr) * (En + Hn);
    int k0 = s * 32 + kg * 8;
    f16x8 v;
    #pragma unroll
    for (int j = 0; j < 8; ++j) v[j] = (f16)row[k0 + j];
    sWA0[mt][s][sl] = v;
  }
  // L1 folded: W[:, :H] + W[:, H:]
  for (int i = 0; i < 8; ++i) {
    int slot = tid * 8 + i;             // 2048 slots
    int sl = slot & 63, s = (slot >> 6) & 15, mt = (slot >> 10) & 1;
    int m = sl & 15, kg = sl >> 4;
    int r = mt * 16 + m, gate = r >> 3, hr = r & 7;
    const float* row = Wg[gate] + ((size_t)Hn + rank * RPB + hr) * (En + Hn);
    int k0 = s * 32 + kg * 8;
    f16x8 v;
    #pragma unroll
    for (int j = 0; j < 8; ++j) v[j] = (f16)(row[k0 + j] + row[k0 + j + Hn]);
    sWA1[mt][s][sl] = v;
  }
  if (tid < 32) {
    int gate = tid >> 3, hr = tid & 7;
    sBiasX[tid] = Bg[gate][0 * Hn + rank * RPB + hr];
    sBias1[tid] = Bg[gate][1 * Hn + rank * RPB + hr];
  }
  if (tid < RPB * BS) sC[tid >> 4][tid & 15] = 0.f;
  // zero hb0 coherently (all blocks write identical zeros — benign)
  for (int i = tid; i < 4096; i += NT) astore(hb0 + i, 0u);

  const int mt = w & 1, kh = w >> 1;
  const int col = l & 15, rbase0 = (l >> 4) << 2;
  // h-store region for this rank: u32 index = (slot)*4 + (hr>>1)
  const int hslot0 = (rank >> 2) * 64 + (rank & 3) * 16;

  u32 phase = 0;

  auto barrier = [&](u32 ph) {
    __syncthreads();   // drains vmcnt: prior agent stores are at coherence point
    if (tid == 0) astore(myFlag, ph);
    if (tid < 64) {
      u32 v = aload(flagG + tid);
      while (__any(v < ph)) { __builtin_amdgcn_s_sleep(4); v = aload(flagG + tid); }
    }
    __syncthreads();
  };

  barrier(++phase);   // publish zeroed hb0

  for (int t = 0; t < Sn; ++t) {
    // ---------- phase A: layer 0, K=1024 ([h from hb0 | x from xb]) -> hb1 ----------
    {
      f32x4 acc = {0.f, 0.f, 0.f, 0.f};
      if (kh == 0) {          // h half: coherent frags from hb0
        f16x8 bfr[16];
        #pragma unroll
        for (int s = 0; s < 16; ++s) bfr[s] = ldfrag(hb0, s * 64 + l);
        #pragma unroll
        for (int s = 0; s < 16; ++s)
          acc = __builtin_amdgcn_mfma_f32_16x16x32_f16(sWA0[mt][s][l], bfr[s], acc, 0, 0, 0);
      } else {                // x half: cached frags from xb
        const f16x8* xbt = xb + ((size_t)(g * Sn + t)) * 1024;
        #pragma unroll
        for (int s = 0; s < 16; ++s)
          acc = __builtin_amdgcn_mfma_f32_16x16x32_f16(sWA0[mt][16 + s][l], xbt[s * 64 + l], acc, 0, 0, 0);
      }
      #pragma unroll
      for (int v = 0; v < 4; ++v) sAcc[kh][mt * 16 + rbase0 + v][col] = acc[v];
    }
    __syncthreads();
    if (tid < RPB * BS) {
      int hr = tid >> 4, b = tid & 15;
      float af = sAcc[0][0 + hr][b] + sAcc[1][0 + hr][b] + sBiasX[0 + hr];
      float ai = sAcc[0][8 + hr][b] + sAcc[1][8 + hr][b] + sBiasX[8 + hr];
      float ac = sAcc[0][16 + hr][b] + sAcc[1][16 + hr][b] + sBiasX[16 + hr];
      float ao = sAcc[0][24 + hr][b] + sAcc[1][24 + hr][b] + sBiasX[24 + hr];
      float ft = sig_(af), it = sig_(ai), ch = tanhf(ac), ot = sig_(ao);
      float c = ft * sC[hr][b] + it * ch;
      sC[hr][b] = c;
      sH[hr][b] = (f16)(ot * tanhf(c));
    }
    __syncthreads();
    if (tid < 64) {  // pack 2 f16 -> u32, coherent store of this rank's 256B
      int b = tid >> 2, q = tid & 3;
      uf16 lo, hi; lo.f = sH[2 * q][b]; hi.f = sH[2 * q + 1][b];
      astore(hb1 + (hslot0 + b) * 4 + q, (u32)lo.u | ((u32)hi.u << 16));
    }
    barrier(++phase);

    // ---------- phase B: layer 1 folded, K=512 (h from hb1) -> hb0 ----------
    {
      f16x8 bfr[8];
      #pragma unroll
      for (int i = 0; i < 8; ++i) bfr[i] = ldfrag(hb1, (kh * 8 + i) * 64 + l);
      f32x4 acc = {0.f, 0.f, 0.f, 0.f};
      #pragma unroll
      for (int i = 0; i < 8; ++i)
        acc = __builtin_amdgcn_mfma_f32_16x16x32_f16(sWA1[mt][kh * 8 + i][l], bfr[i], acc, 0, 0, 0);
      #pragma unroll
      for (int v = 0; v < 4; ++v) sAcc[kh][mt * 16 + rbase0 + v][col] = acc[v];
    }
    __syncthreads();
    if (tid < RPB * BS) {
      int hr = tid >> 4, b = tid & 15;
      float af = sAcc[0][0 + hr][b] + sAcc[1][0 + hr][b] + sBias1[0 + hr];
      float ai = sAcc[0][8 + hr][b] + sAcc[1][8 + hr][b] + sBias1[8 + hr];
      float ac = sAcc[0][16 + hr][b] + sAcc[1][16 + hr][b] + sBias1[16 + hr];
      float ao = sAcc[0][24 + hr][b] + sAcc[1][24 + hr][b] + sBias1[24 + hr];
      float ft = sig_(af), it = sig_(ai), ch = tanhf(ac), ot = sig_(ao);
      float c = ft * sC[hr][b] + it * ch;
      sC[hr][b] = c;
      sH[hr][b] = (f16)(ot * tanhf(c));
    }
    __syncthreads();
    if (tid < 64) {
      int b = tid >> 2, q = tid & 3;
      uf16 lo, hi; lo.f = sH[2 * q][b]; hi.f = sH[2 * q + 1][b];
      astore(hb0 + (hslot0 + b) * 4 + q, (u32)lo.u | ((u32)hi.u << 16));
    }
    barrier(++phase);
  }

  // ---------- epilogue: y = h^T Wy^T + by (rank 0 of each group) ----------
  if (rank == 0) {
    f16* tmp = (f16*)&sWA0[0][0][0];           // reuse LDS
    for (int i = tid; i < 4096; i += NT) ((u32*)tmp)[i] = aload(hb0 + i);
    __syncthreads();
    int kc = tid & 7, o = (tid >> 3) & 1, b = tid >> 4;  // 8 x 2 x 16
    float p = 0.f;
    for (int kk = 0; kk < 64; ++kk) {
      int k = kc * 64 + kk;
      p += (float)tmp[fl_idx(k, b)] * Wy[o * Hn + k];
    }
    sRed[b][o][kc] = p;
    __syncthreads();
    if (tid < BS * OUTn) {
      int b2 = tid >> 1, o2 = tid & 1;
      float s = by[o2];
      #pragma unroll
      for (int q = 0; q < 8; ++q) s += sRed[b2][o2][q];
      out[(g * BS + b2) * OUTn + o2] = s;
    }
  }
}

extern "C" void kernel_launch(void* const* d_in, const int* in_sizes, int n_in,
                              void* d_out, int out_size, void* d_ws, size_t ws_size,
                              hipStream_t stream) {
  const int*   texts = (const int*)d_in[0];
  const float* emb   = (const float*)d_in[1];
  const float* Wf    = (const float*)d_in[2];
  const float* bf    = (const float*)d_in[3];
  const float* Wi    = (const float*)d_in[4];
  const float* bi    = (const float*)d_in[5];
  const float* Wo    = (const float*)d_in[6];
  const float* bo    = (const float*)d_in[7];
  const float* Wc    = (const float*)d_in[8];
  const float* bc    = (const float*)d_in[9];
  const float* Wy    = (const float*)d_in[10];
  const float* by    = (const float*)d_in[11];
  float* out = (float*)d_out;

  f16x8* xbuf    = (f16x8*)((char*)d_ws + XB_OFF);
  char*  hbBase  = (char*)d_ws + HB_OFF;
  u32*   flagBase = (u32*)((char*)d_ws + FLAG_OFF);
  hipMemsetAsync((void*)flagBase, 0, FLAG_SZ, stream);

  xb_fill<<<dim3(NG * Sn), dim3(256), 0, stream>>>(texts, emb, xbuf);

  void* args[] = {(void*)&texts, (void*)&emb, (void*)&Wf, (void*)&bf, (void*)&Wi, (void*)&bi,
                  (void*)&Wo, (void*)&bo, (void*)&Wc, (void*)&bc, (void*)&Wy, (void*)&by,
                  (void*)&out, (void*)&xbuf, (void*)&hbBase, (void*)&flagBase};
  hipLaunchCooperativeKernel((const void*)lstm_mfma, dim3(NB), dim3(NT), args, 0, stream);
}

// Round 7
// 2711.918 us; speedup vs baseline: 19.5287x; 1.6139x over previous
//
#include <hip/hip_runtime.h>

// LSTM V=32000 E=512 H=512 OUT=2 L=2 S=512 B=64 — persistent cooperative kernel.
// R7: 128 blocks x 512 threads; 4 batch-groups x 32 blocks x 16 batch cols.
// Block owns 16 h-rows (64 gate-rows, packed [f,i,c,o] x 16; mtile == gate).
// h staged ONCE per block per phase into LDS via relaxed agent-scope u64 atomic
// loads (coherent), then ds_read b-frags — 8x less coherent traffic than R6.
// L0 A-frags (K=1024, cat [h|x]) in LDS (128 KB); L1 folded A-frags in VGPRs.
// x-part MFMAs for step t+1 run inside barrier-B's wait window (kh==1 waves).
// Fence-free protocol (R6): relaxed agent atomics for h + flags; ordering from
// the vmcnt drain in __syncthreads + poll control dependency.

typedef _Float16 f16;
typedef _Float16 f16x8 __attribute__((ext_vector_type(8)));
typedef float f32x4 __attribute__((ext_vector_type(4)));
typedef unsigned int u32;
typedef unsigned long long u64;
typedef unsigned short u16;

constexpr int Hn = 512, En = 512, Bn = 64, Sn = 512, OUTn = 2;
constexpr int NG = 4, GB = 32, BS = 16, RPB = 16;
constexpr int NB = NG * GB;   // 128 blocks
constexpr int NT = 512;       // 8 waves

// ws layout (bytes)
constexpr size_t XB_OFF = 0;                                 // f16x8 xb[NG][Sn][16][64] = 32 MB
constexpr size_t XB_SZ  = (size_t)NG * Sn * 16 * 64 * 16;
constexpr size_t HB_OFF = XB_OFF + XB_SZ;                    // f16 hb[NG][2], 16 KB each
constexpr size_t HB_SZ  = (size_t)NG * 2 * 16384;
constexpr size_t FLAG_OFF = HB_OFF + HB_SZ;                  // u32 flags, dense per group
constexpr size_t FLAG_SZ  = (size_t)NG * 4096;

__device__ __forceinline__ float sig_(float x) { return 1.f / (1.f + expf(-x)); }

__device__ __forceinline__ u32 aload(const u32* p) {
  return __hip_atomic_load(p, __ATOMIC_RELAXED, __HIP_MEMORY_SCOPE_AGENT);
}
__device__ __forceinline__ void astore(u32* p, u32 v) {
  __hip_atomic_store(p, v, __ATOMIC_RELAXED, __HIP_MEMORY_SCOPE_AGENT);
}
__device__ __forceinline__ u64 aload64(const u64* p) {
  return __hip_atomic_load(p, __ATOMIC_RELAXED, __HIP_MEMORY_SCOPE_AGENT);
}

union uf16 { f16 f; u16 u; };

// coherent 16B fragment load as 2 relaxed agent u64s
__device__ __forceinline__ f16x8 ldfrag2(const u64* base, int frag) {
  union { f16x8 v; u64 q[2]; } u;
  u.q[0] = aload64(base + frag * 2);
  u.q[1] = aload64(base + frag * 2 + 1);
  return u.v;
}

// fragment-linear f16-element index for (k, col), BS=16 cols
__device__ __forceinline__ int fl_idx(int k, int col) {
  return (((k >> 5) * 64 + (((k >> 3) & 3) * 16) + col) << 3) + (k & 7);
}

// -------- pre-pass: gather emb -> fragment-linear f16 xb[g][t] --------
__global__ void __launch_bounds__(256) xb_fill(
    const int* __restrict__ texts, const float* __restrict__ emb,
    f16x8* __restrict__ xb)
{
  const int bidx = blockIdx.x;        // g*Sn + t
  const int g = bidx >> 9, t = bidx & (Sn - 1);
  const int tid = threadIdx.x;
  f16x8* dst = xb + (size_t)bidx * 1024;
  for (int slot = tid; slot < 1024; slot += 256) {
    int s = slot >> 6, sl = slot & 63, kg = sl >> 4, b = sl & 15;
    int idx = texts[t * Bn + g * BS + b];
    const float* er = emb + (size_t)idx * En + s * 32 + kg * 8;
    f16x8 v;
    #pragma unroll
    for (int j = 0; j < 8; ++j) v[j] = (f16)er[j];
    dst[slot] = v;
  }
}

__global__ void __launch_bounds__(NT) lstm_mfma(
    const int* __restrict__ texts, const float* __restrict__ emb,
    const float* __restrict__ Wf, const float* __restrict__ bf,
    const float* __restrict__ Wi, const float* __restrict__ bi,
    const float* __restrict__ Wo, const float* __restrict__ bo,
    const float* __restrict__ Wc, const float* __restrict__ bc,
    const float* __restrict__ Wy, const float* __restrict__ by,
    float* __restrict__ out, const f16x8* __restrict__ xb,
    char* __restrict__ hbBase, u32* __restrict__ flagBase)
{
  __shared__ f16x8 sWA0[4][32][64];    // L0 A-frags, K=1024 cat [h|x], 128 KB
  __shared__ f16x8 sHB[1024];          // staged h (16 KB)
  __shared__ float sAccP[2][64][17];   // phase partials
  __shared__ float sAccX[64][17];      // x-projection partials (next step)
  __shared__ float sBiasX[64], sBias1[64];
  __shared__ float sC[16][16];
  __shared__ f16   sH[16][16];
  __shared__ float sRed[16][2][4];

  const int tid = threadIdx.x;
  const int bid = blockIdx.x;
  const int g = bid & 3;            // under round-robin XCD=bid%8, group g sits on XCDs {g, g+4}
  const int rank = bid >> 2;        // 0..31 within group
  const int w = tid >> 6, l = tid & 63;
  const int mt = w & 3, kh = w >> 2;          // mtile==gate, K-half
  const int col = l & 15, rb = (l >> 4) << 2; // C-frag col / row base

  const float* Wg[4] = {Wf, Wi, Wc, Wo};
  const float* Bg[4] = {bf, bi, bc, bo};

  u32* hb0 = (u32*)(hbBase + (size_t)(g * 2 + 0) * 16384);
  u32* hb1 = (u32*)(hbBase + (size_t)(g * 2 + 1) * 16384);
  u32* flagG  = flagBase + (size_t)g * 1024;
  u32* myFlag = flagG + rank;
  const f16x8* xbG = xb + (size_t)g * Sn * 1024;

  // ---- prologue: L0 A-frags (full cat rows, K=1024) into LDS ----
  for (int i = 0; i < 16; ++i) {
    int slot = tid * 16 + i;              // 8192 slots: [m4][s<32][sl]
    int sl = slot & 63, s = (slot >> 6) & 31, m4 = slot >> 11;
    const float* row = Wg[m4] + (size_t)(rank * RPB + (sl & 15)) * (En + Hn);
    int k0 = s * 32 + (sl >> 4) * 8;
    f16x8 v;
    #pragma unroll
    for (int j = 0; j < 8; ++j) v[j] = (f16)row[k0 + j];
    sWA0[m4][s][sl] = v;
  }
  // L1 folded A-frags in VGPRs (8 per wave)
  f16x8 afr1[8];
  {
    const float* row = Wg[mt] + (size_t)(Hn + rank * RPB + (l & 15)) * (En + Hn);
    #pragma unroll
    for (int i = 0; i < 8; ++i) {
      int k0 = (kh * 8 + i) * 32 + (l >> 4) * 8;
      f16x8 v;
      #pragma unroll
      for (int j = 0; j < 8; ++j) v[j] = (f16)(row[k0 + j] + row[k0 + j + Hn]);
      afr1[i] = v;
    }
  }
  if (tid < 64) {
    int gate = tid >> 4, hr = tid & 15;
    sBiasX[tid] = Bg[gate][rank * RPB + hr];
    sBias1[tid] = Bg[gate][Hn + rank * RPB + hr];
  }
  if (tid < 256) sC[tid >> 4][tid & 15] = 0.f;
  for (int i = tid; i < 4096; i += NT) astore(hb0 + i, 0u);   // identical zeros, benign
  __syncthreads();

  // x-projection for t=0 (kh==1 waves)
  if (kh == 1) {
    f32x4 acc = {0.f, 0.f, 0.f, 0.f};
    #pragma unroll
    for (int s = 0; s < 16; ++s)
      acc = __builtin_amdgcn_mfma_f32_16x16x32_f16(sWA0[mt][16 + s][l], xbG[s * 64 + l], acc, 0, 0, 0);
    #pragma unroll
    for (int v = 0; v < 4; ++v) sAccX[mt * 16 + rb + v][col] = acc[v];
  }

  u32 phase = 0;

  // initial barrier (publishes zeroed hb0)
  __syncthreads();
  ++phase;
  if (tid == 0) astore(myFlag, phase);
  if (tid < 32) {
    u32 v = aload(flagG + tid);
    while (__any(v < phase)) { __builtin_amdgcn_s_sleep(1); v = aload(flagG + tid); }
  }
  __syncthreads();

  for (int t = 0; t < Sn; ++t) {
    // ---------- phase A: layer 0 -> hb1 ----------
    {  // stage hb0 -> LDS (each wave 2 KB)
      const u64* src = (const u64*)hb0;
      #pragma unroll
      for (int j = 0; j < 2; ++j) { int f = w * 128 + j * 64 + l; sHB[f] = ldfrag2(src, f); }
    }
    __syncthreads();
    {  // h-part MFMAs: 8 per wave
      f32x4 acc = {0.f, 0.f, 0.f, 0.f};
      #pragma unroll
      for (int i = 0; i < 8; ++i) {
        int s = kh * 8 + i;
        acc = __builtin_amdgcn_mfma_f32_16x16x32_f16(sWA0[mt][s][l], sHB[s * 64 + l], acc, 0, 0, 0);
      }
      #pragma unroll
      for (int v = 0; v < 4; ++v) sAccP[kh][mt * 16 + rb + v][col] = acc[v];
    }
    __syncthreads();
    if (tid < 256) {  // gate update L0
      int hr = tid >> 4, b = tid & 15;
      float af = sAccP[0][ 0 + hr][b] + sAccP[1][ 0 + hr][b] + sAccX[ 0 + hr][b] + sBiasX[ 0 + hr];
      float ai = sAccP[0][16 + hr][b] + sAccP[1][16 + hr][b] + sAccX[16 + hr][b] + sBiasX[16 + hr];
      float ac = sAccP[0][32 + hr][b] + sAccP[1][32 + hr][b] + sAccX[32 + hr][b] + sBiasX[32 + hr];
      float ao = sAccP[0][48 + hr][b] + sAccP[1][48 + hr][b] + sAccX[48 + hr][b] + sBiasX[48 + hr];
      float ft = sig_(af), it = sig_(ai), ch = tanhf(ac), ot = sig_(ao);
      float c = ft * sC[hr][b] + it * ch;
      sC[hr][b] = c;
      sH[hr][b] = (f16)(ot * tanhf(c));
    }
    __syncthreads();
    if (tid < 128) {  // pack + coherent store of this rank's 512 B
      int q = tid >> 4, b = tid & 15;
      int k0 = rank * RPB + 2 * q;
      uf16 lo, hi; lo.f = sH[2 * q][b]; hi.f = sH[2 * q + 1][b];
      int slot = (k0 >> 5) * 64 + ((k0 >> 3) & 3) * 16 + b;
      astore(hb1 + slot * 4 + (q & 3), (u32)lo.u | ((u32)hi.u << 16));
    }
    // barrier A
    __syncthreads();
    ++phase;
    if (tid == 0) astore(myFlag, phase);
    if (tid < 32) {
      u32 v = aload(flagG + tid);
      while (__any(v < phase)) { __builtin_amdgcn_s_sleep(1); v = aload(flagG + tid); }
    }
    __syncthreads();

    // ---------- phase B: layer 1 folded -> hb0 ----------
    {  // stage hb1 -> LDS
      const u64* src = (const u64*)hb1;
      #pragma unroll
      for (int j = 0; j < 2; ++j) { int f = w * 128 + j * 64 + l; sHB[f] = ldfrag2(src, f); }
    }
    __syncthreads();
    {  // MFMAs with VGPR A-frags
      f32x4 acc = {0.f, 0.f, 0.f, 0.f};
      #pragma unroll
      for (int i = 0; i < 8; ++i)
        acc = __builtin_amdgcn_mfma_f32_16x16x32_f16(afr1[i], sHB[(kh * 8 + i) * 64 + l], acc, 0, 0, 0);
      #pragma unroll
      for (int v = 0; v < 4; ++v) sAccP[kh][mt * 16 + rb + v][col] = acc[v];
    }
    __syncthreads();
    if (tid < 256) {  // gate update L1
      int hr = tid >> 4, b = tid & 15;
      float af = sAccP[0][ 0 + hr][b] + sAccP[1][ 0 + hr][b] + sBias1[ 0 + hr];
      float ai = sAccP[0][16 + hr][b] + sAccP[1][16 + hr][b] + sBias1[16 + hr];
      float ac = sAccP[0][32 + hr][b] + sAccP[1][32 + hr][b] + sBias1[32 + hr];
      float ao = sAccP[0][48 + hr][b] + sAccP[1][48 + hr][b] + sBias1[48 + hr];
      float ft = sig_(af), it = sig_(ai), ch = tanhf(ac), ot = sig_(ao);
      float c = ft * sC[hr][b] + it * ch;
      sC[hr][b] = c;
      sH[hr][b] = (f16)(ot * tanhf(c));
    }
    __syncthreads();
    if (tid < 128) {
      int q = tid >> 4, b = tid & 15;
      int k0 = rank * RPB + 2 * q;
      uf16 lo, hi; lo.f = sH[2 * q][b]; hi.f = sH[2 * q + 1][b];
      int slot = (k0 >> 5) * 64 + ((k0 >> 3) & 3) * 16 + b;
      astore(hb0 + slot * 4 + (q & 3), (u32)lo.u | ((u32)hi.u << 16));
    }
    // barrier B, x-MFMAs for t+1 hidden in the wait window
    __syncthreads();
    ++phase;
    if (tid == 0) astore(myFlag, phase);
    if (kh == 1 && t + 1 < Sn) {
      const f16x8* xbt = xbG + (size_t)(t + 1) * 1024;
      f32x4 acc = {0.f, 0.f, 0.f, 0.f};
      #pragma unroll
      for (int s = 0; s < 16; ++s)
        acc = __builtin_amdgcn_mfma_f32_16x16x32_f16(sWA0[mt][16 + s][l], xbt[s * 64 + l], acc, 0, 0, 0);
      #pragma unroll
      for (int v = 0; v < 4; ++v) sAccX[mt * 16 + rb + v][col] = acc[v];
    }
    if (tid < 32) {
      u32 v = aload(flagG + tid);
      while (__any(v < phase)) { __builtin_amdgcn_s_sleep(1); v = aload(flagG + tid); }
    }
    __syncthreads();
  }

  // ---------- epilogue: y = h^T Wy^T + by (rank 0 of each group) ----------
  if (rank == 0) {
    f16* tmp = (f16*)&sWA0[0][0][0];           // reuse LDS
    for (int i = tid; i < 4096; i += NT) ((u32*)tmp)[i] = aload(hb0 + i);
    __syncthreads();
    if (tid < 128) {
      int b = tid >> 3, o = (tid >> 2) & 1, kc = tid & 3;   // 16 x 2 x 4
      float p = 0.f;
      for (int kk = 0; kk < 128; ++kk) {
        int k = kc * 128 + kk;
        p += (float)tmp[fl_idx(k, b)] * Wy[o * Hn + k];
      }
      sRed[b][o][kc] = p;
    }
    __syncthreads();
    if (tid < 32) {
      int b2 = tid >> 1, o2 = tid & 1;
      float s = by[o2];
      #pragma unroll
      for (int q = 0; q < 4; ++q) s += sRed[b2][o2][q];
      out[(g * BS + b2) * OUTn + o2] = s;
    }
  }
}

extern "C" void kernel_launch(void* const* d_in, const int* in_sizes, int n_in,
                              void* d_out, int out_size, void* d_ws, size_t ws_size,
                              hipStream_t stream) {
  const int*   texts = (const int*)d_in[0];
  const float* emb   = (const float*)d_in[1];
  const float* Wf    = (const float*)d_in[2];
  const float* bf    = (const float*)d_in[3];
  const float* Wi    = (const float*)d_in[4];
  const float* bi    = (const float*)d_in[5];
  const float* Wo    = (const float*)d_in[6];
  const float* bo    = (const float*)d_in[7];
  const float* Wc    = (const float*)d_in[8];
  const float* bc    = (const float*)d_in[9];
  const float* Wy    = (const float*)d_in[10];
  const float* by    = (const float*)d_in[11];
  float* out = (float*)d_out;

  f16x8* xbuf     = (f16x8*)((char*)d_ws + XB_OFF);
  char*  hbBase   = (char*)d_ws + HB_OFF;
  u32*   flagBase = (u32*)((char*)d_ws + FLAG_OFF);
  hipMemsetAsync((void*)flagBase, 0, FLAG_SZ, stream);

  xb_fill<<<dim3(NG * Sn), dim3(256), 0, stream>>>(texts, emb, xbuf);

  void* args[] = {(void*)&texts, (void*)&emb, (void*)&Wf, (void*)&bf, (void*)&Wi, (void*)&bi,
                  (void*)&Wo, (void*)&bo, (void*)&Wc, (void*)&bc, (void*)&Wy, (void*)&by,
                  (void*)&out, (void*)&xbuf, (void*)&hbBase, (void*)&flagBase};
  hipLaunchCooperativeKernel((const void*)lstm_mfma, dim3(NB), dim3(NT), args, 0, stream);
}